// Round 7
// baseline (259.987 us; speedup 1.0000x reference)
//
#include <hip/hip_runtime.h>
#include <hip/hip_bf16.h>

// Problem constants: B=2, T=2048, E=1024, H=16, D=64
#define T_DIM 2048
#define E_DIM 1024
#define MM 4096   // B*T
#define NN 1024
#define KK 1024
#define MSZ ((size_t)MM * KK)   // 4M elems per activation matrix
#define WSZ ((size_t)NN * KK)   // 1M elems per weight matrix

typedef __attribute__((ext_vector_type(8))) short bh8;   // 8 x bf16
typedef __attribute__((ext_vector_type(4))) short bh4;   // 4 x bf16
typedef __attribute__((ext_vector_type(4))) float fx4;   // MFMA accumulator
typedef __attribute__((ext_vector_type(4))) unsigned ux4;

#define QSCALE 0.18033688f   // 1/sqrt(64) * log2(e), folded into Wq

// HW RNE f32->bf16 (single instr; identical rounding to manual RNE)
static __device__ __forceinline__ short f2bf(float f) {
  unsigned o;
  asm("v_cvt_pk_bf16_f32 %0, %1, %1" : "=v"(o) : "v"(f));
  return (short)(o & 0xffffu);
}
// packed pair
static __device__ __forceinline__ unsigned f2bf2(float lo, float hi) {
  unsigned o;
  asm("v_cvt_pk_bf16_f32 %0, %1, %2" : "=v"(o) : "v"(lo), "v"(hi));
  return o;
}

static __device__ __forceinline__ void gload16(const void* g, void* l) {
  __builtin_amdgcn_global_load_lds(
      (const __attribute__((address_space(1))) unsigned*)g,
      (__attribute__((address_space(3))) unsigned*)l, 16, 0, 0);
}

// DPP lane-rotate within 16-lane row: pure-VALU cross-lane (no LDS pipe)
template<int CTRL>
static __device__ __forceinline__ float dppf(float x) {
  union { float f; int i; } a, b;
  a.f = x;
  b.i = __builtin_amdgcn_update_dpp(0, a.i, CTRL, 0xf, 0xf, false);
  return b.f;
}
static __device__ __forceinline__ float rowmax16(float x) {
  x = fmaxf(x, dppf<0x121>(x));
  x = fmaxf(x, dppf<0x122>(x));
  x = fmaxf(x, dppf<0x124>(x));
  x = fmaxf(x, dppf<0x128>(x));
  return x;
}
static __device__ __forceinline__ float rowsum16(float x) {
  x += dppf<0x121>(x);
  x += dppf<0x122>(x);
  x += dppf<0x124>(x);
  x += dppf<0x128>(x);
  return x;
}

// ---- f32 -> bf16 conversions; Wq (a==0) pre-scaled by QSCALE ----
__global__ __launch_bounds__(256) void cvt_w(const float* __restrict__ s0,
                                             const float* __restrict__ s1,
                                             const float* __restrict__ s2,
                                             const float* __restrict__ s3,
                                             short* __restrict__ dst) {
  int a = blockIdx.y;
  const float* sp = a == 0 ? s0 : a == 1 ? s1 : a == 2 ? s2 : s3;
  const float sc = (a == 0) ? QSCALE : 1.0f;
  size_t i = ((size_t)blockIdx.x * 256 + threadIdx.x) * 8;
  fx4 x = *(const fx4*)(sp + i);
  fx4 y = *(const fx4*)(sp + i + 4);
  ux4 o;
  o[0] = f2bf2(x[0] * sc, x[1] * sc);
  o[1] = f2bf2(x[2] * sc, x[3] * sc);
  o[2] = f2bf2(y[0] * sc, y[1] * sc);
  o[3] = f2bf2(y[2] * sc, y[3] * sc);
  *(ux4*)(dst + (size_t)a * WSZ + i) = o;
}

__global__ __launch_bounds__(256) void cvt_act(const float* __restrict__ s0,
                                               const float* __restrict__ s1,
                                               const float* __restrict__ s2,
                                               short* __restrict__ dst) {
  int a = blockIdx.y;
  const float* sp = a == 0 ? s0 : a == 1 ? s1 : s2;
  size_t i = ((size_t)blockIdx.x * 256 + threadIdx.x) * 8;
  fx4 x = *(const fx4*)(sp + i);
  fx4 y = *(const fx4*)(sp + i + 4);
  ux4 o;
  o[0] = f2bf2(x[0], x[1]);
  o[1] = f2bf2(x[2], x[3]);
  o[2] = f2bf2(y[0], y[1]);
  o[3] = f2bf2(y[2], y[3]);
  *(ux4*)(dst + (size_t)a * MSZ + i) = o;
}

// ---- NT GEMM, BK=64 via dual 32-k buffers (m97 banking, half the barriers) ----
template<bool OUTF32>
__global__ __launch_bounds__(256) void gemm_fast(const short* __restrict__ A0,
                                                 const short* __restrict__ A1,
                                                 const short* __restrict__ A2,
                                                 const short* __restrict__ W0,
                                                 void* __restrict__ C0)
{
  __shared__ short As[2][128 * 32];
  __shared__ short Bs[2][128 * 32];
  const int tid = threadIdx.x;
  const int lane = tid & 63, w = tid >> 6;
  const int lm = lane & 15, lg = lane >> 4;
  const int wr = w >> 1, wc = w & 1;
  const int m0 = blockIdx.y * 128, n0 = blockIdx.x * 128;
  const int z = blockIdx.z;
  const short* Ab = z == 0 ? A0 : z == 1 ? A1 : A2;
  const short* W = W0 + (size_t)z * WSZ;

  fx4 acc[4][4] = {};

  for (int k0 = 0; k0 < KK; k0 += 64) {
    __syncthreads();
#pragma unroll
    for (int h = 0; h < 2; h++) {
#pragma unroll
      for (int c = 0; c < 2; c++) {
        int idx = c * 256 + tid;
        int row = idx >> 2, kc = idx & 3;
        gload16(W + (size_t)(n0 + row) * KK + k0 + h * 32 + kc * 8, &Bs[h][idx * 8]);
        gload16(Ab + (size_t)(m0 + row) * KK + k0 + h * 32 + kc * 8, &As[h][idx * 8]);
      }
    }
    __syncthreads();
    bh8 af[4][2], bf[4][2];
#pragma unroll
    for (int mi = 0; mi < 4; mi++)
#pragma unroll
      for (int h = 0; h < 2; h++)
        af[mi][h] = *(const bh8*)&As[h][(wr * 64 + mi * 16 + lm) * 32 + lg * 8];
#pragma unroll
    for (int ni = 0; ni < 4; ni++)
#pragma unroll
      for (int h = 0; h < 2; h++)
        bf[ni][h] = *(const bh8*)&Bs[h][(wc * 64 + ni * 16 + lm) * 32 + lg * 8];
#pragma unroll
    for (int mi = 0; mi < 4; mi++)
#pragma unroll
      for (int ni = 0; ni < 4; ni++)
#pragma unroll
        for (int h = 0; h < 2; h++)
          acc[mi][ni] = __builtin_amdgcn_mfma_f32_16x16x32_bf16(af[mi][h], bf[ni][h], acc[mi][ni], 0, 0, 0);
  }

#pragma unroll
  for (int mi = 0; mi < 4; mi++)
#pragma unroll
    for (int ni = 0; ni < 4; ni++) {
      int row = m0 + wr * 64 + mi * 16 + lg * 4;
      int col = n0 + wc * 64 + ni * 16 + lm;
#pragma unroll
      for (int r = 0; r < 4; r++) {
        float vv = acc[mi][ni][r];
        if constexpr (OUTF32) ((float*)C0)[(size_t)z * MSZ + (size_t)(row + r) * NN + col] = vv;
        else ((short*)C0)[(size_t)z * MSZ + (size_t)(row + r) * NN + col] = f2bf(vv);
      }
    }
}

// ---- out-projection GEMM: 64x128 tiles, BK=64 dual buffer, XCD swizzle ----
__global__ __launch_bounds__(256) void gemm_out64(const short* __restrict__ A,
                                                  const short* __restrict__ W,
                                                  float* __restrict__ C)
{
  __shared__ short As[2][64 * 32];
  __shared__ short Bs[2][128 * 32];
  const int tid = threadIdx.x;
  const int lane = tid & 63, w = tid >> 6;
  const int lm = lane & 15, lg = lane >> 4;
  const int lin = blockIdx.x + 8 * blockIdx.y;
  const int swz = (lin & 7) * 64 + (lin >> 3);
  const int n0 = (swz & 7) * 128, m0 = (swz >> 3) * 64;

  fx4 acc[4][2] = {};

  for (int k0 = 0; k0 < KK; k0 += 64) {
    __syncthreads();
#pragma unroll
    for (int h = 0; h < 2; h++) {
      {
        int row = tid >> 2, kc = tid & 3;
        gload16(A + (size_t)(m0 + row) * KK + k0 + h * 32 + kc * 8, &As[h][tid * 8]);
      }
#pragma unroll
      for (int c = 0; c < 2; c++) {
        int idx = c * 256 + tid;
        int brow = idx >> 2, bkc = idx & 3;
        gload16(W + (size_t)(n0 + brow) * KK + k0 + h * 32 + bkc * 8, &Bs[h][idx * 8]);
      }
    }
    __syncthreads();
    bh8 af[4][2], bf[2][2];
#pragma unroll
    for (int mi = 0; mi < 4; mi++)
#pragma unroll
      for (int h = 0; h < 2; h++)
        af[mi][h] = *(const bh8*)&As[h][(mi * 16 + lm) * 32 + lg * 8];
#pragma unroll
    for (int ni = 0; ni < 2; ni++)
#pragma unroll
      for (int h = 0; h < 2; h++)
        bf[ni][h] = *(const bh8*)&Bs[h][(w * 32 + ni * 16 + lm) * 32 + lg * 8];
#pragma unroll
    for (int mi = 0; mi < 4; mi++)
#pragma unroll
      for (int ni = 0; ni < 2; ni++)
#pragma unroll
        for (int h = 0; h < 2; h++)
          acc[mi][ni] = __builtin_amdgcn_mfma_f32_16x16x32_bf16(af[mi][h], bf[ni][h], acc[mi][ni], 0, 0, 0);
  }

#pragma unroll
  for (int mi = 0; mi < 4; mi++)
#pragma unroll
    for (int ni = 0; ni < 2; ni++) {
      int row = m0 + mi * 16 + lg * 4;
      int col = n0 + w * 32 + ni * 16 + lm;
#pragma unroll
      for (int r = 0; r < 4; r++)
        C[(size_t)(row + r) * NN + col] = acc[mi][ni][r];
    }
}

// ---- fallback GEMM (f32 weights, reg-staged, padded LDS) ----
template<bool AF32, bool OUTF32>
__global__ __launch_bounds__(256) void gemm_nt(const void* __restrict__ Ap,
                                               const float* __restrict__ Bw,
                                               void* __restrict__ Cp,
                                               int M, int N, int K)
{
  __shared__ short As[128 * 40];
  __shared__ short Bs[128 * 40];
  const int tid = threadIdx.x;
  const int lane = tid & 63;
  const int w = tid >> 6;
  const int lm = lane & 15;
  const int lg = lane >> 4;
  const int wr = w >> 1, wc = w & 1;
  const int m0 = blockIdx.y * 128, n0 = blockIdx.x * 128;

  fx4 acc[4][4] = {};

  for (int k0 = 0; k0 < K; k0 += 32) {
    __syncthreads();
#pragma unroll
    for (int i = 0; i < 4; ++i) {
      int g = i * 256 + tid;
      int row = g >> 3, cg = g & 7;
      bh4 a4;
      if constexpr (AF32) {
        const float* A = (const float*)Ap;
        fx4 v = *(const fx4*)(A + (size_t)(m0 + row) * K + k0 + cg * 4);
#pragma unroll
        for (int j = 0; j < 4; j++) a4[j] = f2bf(v[j]);
      } else {
        const short* A = (const short*)Ap;
        a4 = *(const bh4*)(A + (size_t)(m0 + row) * K + k0 + cg * 4);
      }
      *(bh4*)&As[row * 40 + cg * 4] = a4;

      fx4 bv = *(const fx4*)(Bw + (size_t)(n0 + row) * K + k0 + cg * 4);
      bh4 b4;
#pragma unroll
      for (int j = 0; j < 4; j++) b4[j] = f2bf(bv[j]);
      *(bh4*)&Bs[row * 40 + cg * 4] = b4;
    }
    __syncthreads();

    bh8 af[4], bf[4];
#pragma unroll
    for (int mi = 0; mi < 4; mi++)
      af[mi] = *(const bh8*)&As[(wr * 64 + mi * 16 + lm) * 40 + lg * 8];
#pragma unroll
    for (int ni = 0; ni < 4; ni++)
      bf[ni] = *(const bh8*)&Bs[(wc * 64 + ni * 16 + lm) * 40 + lg * 8];
#pragma unroll
    for (int mi = 0; mi < 4; mi++)
#pragma unroll
      for (int ni = 0; ni < 4; ni++)
        acc[mi][ni] = __builtin_amdgcn_mfma_f32_16x16x32_bf16(af[mi], bf[ni], acc[mi][ni], 0, 0, 0);
  }

#pragma unroll
  for (int mi = 0; mi < 4; mi++) {
#pragma unroll
    for (int ni = 0; ni < 4; ni++) {
      int row = m0 + wr * 64 + mi * 16 + lg * 4;
      int col = n0 + wc * 64 + ni * 16 + lm;
#pragma unroll
      for (int r = 0; r < 4; r++) {
        float vv = acc[mi][ni][r];
        if constexpr (OUTF32) ((float*)Cp)[(size_t)(row + r) * N + col] = vv;
        else        ((short*)Cp)[(size_t)(row + r) * N + col] = f2bf(vv);
      }
    }
  }
}

// ---- causal flash attention, paired q-tiles, dbuf K/V, DPP softmax, defer-max ----
// grid (16, 32), XCD-swizzled so each XCD owns 4 heads (K/V 2MB, L2-resident)
// PRESCALED: Q already carries 1/sqrt(D)*log2(e)
template<bool PRESCALED>
__global__ __launch_bounds__(256) void attn_kernel(const short* __restrict__ Q,
                                                   const short* __restrict__ Kb,
                                                   const short* __restrict__ Vb,
                                                   short* __restrict__ At)
{
  __shared__ short Kl[2][64 * 64]; // [kv][d] chunks, src-swizzled: LDS[row][ch] = K[row][ch^(row&7)]
  __shared__ short Vt[2][64 * 64]; // V^T [d][kv], chunk-swizzled by g(d)=((d>>3)+(d&7))&7
  __shared__ short Pl[4 * 16 * 72];// per-wave P [16 q][64 kv], stride 72

  const int tid = threadIdx.x;
  const int lane = tid & 63;
  const int w = tid >> 6;
  const int lm = lane & 15;
  const int lg = lane >> 4;
  const int lin = blockIdx.x + 16 * blockIdx.y;
  const int swz = (lin & 7) * 64 + (lin >> 3);
  const int pi = swz & 15;
  const int bh = swz >> 4;
  const size_t headoff = (size_t)(bh >> 4) * T_DIM * E_DIM + (size_t)(bh & 15) * 64;

  const float SCALE2 = QSCALE;

  const int r0 = tid >> 3, ch0 = tid & 7;
  const int r1 = (256 + tid) >> 3, ch1 = tid & 7;

  for (int s = 0; s < 2; s++) {
    const int qt = s ? (31 - pi) : pi;
    const int q0 = qt * 64;

    const int qrow = q0 + w * 16 + lm;
    bh8 qf[2];
#pragma unroll
    for (int ks = 0; ks < 2; ks++)
      qf[ks] = *(const bh8*)(Q + headoff + (size_t)qrow * E_DIM + ks * 32 + lg * 8);

    fx4 oacc[4] = {};
    float m_r[4], l_r[4];
#pragma unroll
    for (int r = 0; r < 4; r++) { m_r[r] = -INFINITY; l_r[r] = 0.0f; }

    // prologue: stage tile 0 into buffer 0
    {
      gload16(Kb + headoff + (size_t)r0 * E_DIM + ((ch0 ^ (r0 & 7)) * 8), &Kl[0][tid * 8]);
      gload16(Kb + headoff + (size_t)r1 * E_DIM + ((ch1 ^ (r1 & 7)) * 8), &Kl[0][(256 + tid) * 8]);
      bh8 v8a = *(const bh8*)(Vb + headoff + (size_t)r0 * E_DIM + ch0 * 8);
      bh8 v8b = *(const bh8*)(Vb + headoff + (size_t)r1 * E_DIM + ch1 * 8);
#pragma unroll
      for (int j = 0; j < 8; j++) {
        int d = ch0 * 8 + j;
        Vt[0][d * 64 + (((r0 >> 3) ^ ((ch0 + j) & 7)) * 8) + (r0 & 7)] = v8a[j];
        Vt[0][d * 64 + (((r1 >> 3) ^ ((ch1 + j) & 7)) * 8) + (r1 & 7)] = v8b[j];
      }
    }
    __syncthreads();

    int cur = 0;
    for (int t = 0; t <= qt; ++t) {
      const bool pre = (t < qt);
      bh8 v8a, v8b;
      if (pre) {
        const int kvn = (t + 1) * 64;
        gload16(Kb + headoff + (size_t)(kvn + r0) * E_DIM + ((ch0 ^ (r0 & 7)) * 8),
                &Kl[cur ^ 1][tid * 8]);
        gload16(Kb + headoff + (size_t)(kvn + r1) * E_DIM + ((ch1 ^ (r1 & 7)) * 8),
                &Kl[cur ^ 1][(256 + tid) * 8]);
        v8a = *(const bh8*)(Vb + headoff + (size_t)(kvn + r0) * E_DIM + ch0 * 8);
        v8b = *(const bh8*)(Vb + headoff + (size_t)(kvn + r1) * E_DIM + ch1 * 8);
      }

      // S = Q K^T from Kl[cur]
      fx4 sacc[4] = {};
#pragma unroll
      for (int nb = 0; nb < 4; nb++) {
        const int rK = nb * 16 + lm;
#pragma unroll
        for (int ks = 0; ks < 2; ks++) {
          bh8 kf = *(const bh8*)&Kl[cur][rK * 64 + (((ks * 4 + lg) ^ (lm & 7)) * 8)];
          sacc[nb] = __builtin_amdgcn_mfma_f32_16x16x32_bf16(qf[ks], kf, sacc[nb], 0, 0, 0);
        }
      }

      // (optional scale) + causal mask (diagonal tile only)
      float sv[4][4];
      const bool maskt = (t == qt);
#pragma unroll
      for (int nb = 0; nb < 4; nb++)
#pragma unroll
        for (int r = 0; r < 4; r++) {
          float x = PRESCALED ? sacc[nb][r] : sacc[nb][r] * SCALE2;
          if (maskt && (nb * 16 + lm > w * 16 + lg * 4 + r)) x = -INFINITY;
          sv[nb][r] = x;
        }

      // row maxes (DPP) + defer-max: skip rescale when no row max grew
      float rm4[4];
      bool stable = true;
#pragma unroll
      for (int r = 0; r < 4; r++) {
        float rm = fmaxf(fmaxf(sv[0][r], sv[1][r]), fmaxf(sv[2][r], sv[3][r]));
        rm = rowmax16(rm);
        rm4[r] = rm;
        stable = stable && (rm <= m_r[r]);
      }
      if (!__all(stable)) {
#pragma unroll
        for (int r = 0; r < 4; r++) {
          float mn = fmaxf(m_r[r], rm4[r]);
          float fac = exp2f(m_r[r] - mn);
          l_r[r] *= fac;
          m_r[r] = mn;
#pragma unroll
          for (int db = 0; db < 4; db++) oacc[db][r] *= fac;
        }
      }
      float p[4][4];
#pragma unroll
      for (int r = 0; r < 4; r++) {
        float ps = 0.0f;
#pragma unroll
        for (int nb = 0; nb < 4; nb++) { p[nb][r] = exp2f(sv[nb][r] - m_r[r]); ps += p[nb][r]; }
        ps = rowsum16(ps);
        l_r[r] += ps;
      }

      // P -> per-wave LDS (no barrier: per-wave private, same-wave DS in-order)
#pragma unroll
      for (int nb = 0; nb < 4; nb++)
#pragma unroll
        for (int r = 0; r < 4; r++)
          Pl[w * 1152 + (lg * 4 + r) * 72 + nb * 16 + lm] = f2bf(p[nb][r]);

      // O += P V from Vt[cur]
      bh8 pa[2];
#pragma unroll
      for (int ks = 0; ks < 2; ks++)
        pa[ks] = *(const bh8*)&Pl[w * 1152 + lm * 72 + ks * 32 + lg * 8];
#pragma unroll
      for (int db = 0; db < 4; db++) {
        const int d = db * 16 + lm;
        const int gsw = ((d >> 3) + (d & 7)) & 7;
#pragma unroll
        for (int ks = 0; ks < 2; ks++) {
          bh8 vf = *(const bh8*)&Vt[cur][d * 64 + (((ks * 4 + lg) ^ gsw) * 8)];
          oacc[db] = __builtin_amdgcn_mfma_f32_16x16x32_bf16(pa[ks], vf, oacc[db], 0, 0, 0);
        }
      }

      // scatter prefetched V (reg-dep wait lands here, after compute)
      if (pre) {
#pragma unroll
        for (int j = 0; j < 8; j++) {
          int d = ch0 * 8 + j;
          Vt[cur ^ 1][d * 64 + (((r0 >> 3) ^ ((ch0 + j) & 7)) * 8) + (r0 & 7)] = v8a[j];
          Vt[cur ^ 1][d * 64 + (((r1 >> 3) ^ ((ch1 + j) & 7)) * 8) + (r1 & 7)] = v8b[j];
        }
      }
      __syncthreads();
      cur ^= 1;
    }

    // epilogue
#pragma unroll
    for (int r = 0; r < 4; r++) {
      float rl = 1.0f / l_r[r];
      int row = q0 + w * 16 + lg * 4 + r;
#pragma unroll
      for (int db = 0; db < 4; db++)
        At[headoff + (size_t)row * E_DIM + db * 16 + lm] = f2bf(oacc[db][r] * rl);
    }
  }
}

extern "C" void kernel_launch(void* const* d_in, const int* in_sizes, int n_in,
                              void* d_out, int out_size, void* d_ws, size_t ws_size,
                              hipStream_t stream)
{
  const float* q  = (const float*)d_in[0];
  const float* k  = (const float*)d_in[1];
  const float* v  = (const float*)d_in[2];
  // d_in[3] = causal mask, statically known -> ignored
  const float* Wq = (const float*)d_in[4];
  const float* Wk = (const float*)d_in[5];
  const float* Wv = (const float*)d_in[6];
  const float* Wo = (const float*)d_in[7];

  short* Qb  = (short*)d_ws;            // 3 x [4096,1024] bf16 projections
  short* Kbb = Qb + MSZ;
  short* Vbb = Kbb + MSZ;
  short* wqb = Vbb + MSZ;               // 4 x [1024,1024] bf16 weights (Wq pre-scaled)
  short* Xq  = wqb + 4 * WSZ;           // 3 x [4096,1024] bf16 activations
  short* At  = Xq;                      // alias: At live only after Xq dead

  const size_t need_full = (3 * MSZ + 4 * WSZ + 3 * MSZ) * 2;      // ~56 MB

  if (ws_size >= need_full) {
    cvt_act<<<dim3(MSZ / (256 * 8), 3), 256, 0, stream>>>(q, k, v, Xq);
    cvt_w<<<dim3(WSZ / (256 * 8), 4), 256, 0, stream>>>(Wq, Wk, Wv, Wo, wqb);
    gemm_fast<false><<<dim3(NN / 128, MM / 128, 3), 256, 0, stream>>>(
        Xq, Xq + MSZ, Xq + 2 * MSZ, wqb, Qb);
    attn_kernel<true><<<dim3(16, 32), 256, 0, stream>>>(Qb, Kbb, Vbb, At);
    gemm_out64<<<dim3(NN / 128, MM / 64), 256, 0, stream>>>(
        At, wqb + 3 * WSZ, (float*)d_out);
  } else {
    short* At2 = Vbb + MSZ;
    dim3 gg(NN / 128, MM / 128);
    gemm_nt<true, false><<<gg, 256, 0, stream>>>(q, Wq, Qb, MM, NN, KK);
    gemm_nt<true, false><<<gg, 256, 0, stream>>>(k, Wk, Kbb, MM, NN, KK);
    gemm_nt<true, false><<<gg, 256, 0, stream>>>(v, Wv, Vbb, MM, NN, KK);
    attn_kernel<false><<<dim3(16, 32), 256, 0, stream>>>(Qb, Kbb, Vbb, At2);
    gemm_nt<false, true><<<gg, 256, 0, stream>>>(At2, Wo, d_out, MM, NN, KK);
  }
}

// Round 8
// 242.192 us; speedup vs baseline: 1.0735x; 1.0735x over previous
//
#include <hip/hip_runtime.h>
#include <hip/hip_bf16.h>

// Problem constants: B=2, T=2048, E=1024, H=16, D=64
#define T_DIM 2048
#define E_DIM 1024
#define MM 4096   // B*T
#define NN 1024
#define KK 1024
#define MSZ ((size_t)MM * KK)   // 4M elems per activation matrix
#define WSZ ((size_t)NN * KK)   // 1M elems per weight matrix

typedef __attribute__((ext_vector_type(8))) short bh8;   // 8 x bf16
typedef __attribute__((ext_vector_type(4))) short bh4;   // 4 x bf16
typedef __attribute__((ext_vector_type(4))) float fx4;   // MFMA accumulator

#define QSCALE 0.18033688f   // 1/sqrt(64) * log2(e), folded into Wq

// manual RNE f32->bf16 (round-6 proven; m240: do NOT hand-write cvt_pk asm)
static __device__ __forceinline__ short f2bf(float f) {
  union { float f; unsigned u; } v; v.f = f;
  unsigned r = (v.u + 0x7fffu + ((v.u >> 16) & 1u)) >> 16;
  return (short)(unsigned short)r;
}

static __device__ __forceinline__ void gload16(const void* g, void* l) {
  __builtin_amdgcn_global_load_lds(
      (const __attribute__((address_space(1))) unsigned*)g,
      (__attribute__((address_space(3))) unsigned*)l, 16, 0, 0);
}

// DPP lane-rotate within 16-lane row: pure-VALU cross-lane (no LDS pipe)
template<int CTRL>
static __device__ __forceinline__ float dppf(float x) {
  union { float f; int i; } a, b;
  a.f = x;
  b.i = __builtin_amdgcn_update_dpp(0, a.i, CTRL, 0xf, 0xf, false);
  return b.f;
}
static __device__ __forceinline__ float rowmax16(float x) {
  x = fmaxf(x, dppf<0x121>(x));
  x = fmaxf(x, dppf<0x122>(x));
  x = fmaxf(x, dppf<0x124>(x));
  x = fmaxf(x, dppf<0x128>(x));
  return x;
}
static __device__ __forceinline__ float rowsum16(float x) {
  x += dppf<0x121>(x);
  x += dppf<0x122>(x);
  x += dppf<0x124>(x);
  x += dppf<0x128>(x);
  return x;
}

// ---- f32 -> bf16 conversions; Wq (a==0) pre-scaled by QSCALE ----
__global__ __launch_bounds__(256) void cvt_w(const float* __restrict__ s0,
                                             const float* __restrict__ s1,
                                             const float* __restrict__ s2,
                                             const float* __restrict__ s3,
                                             short* __restrict__ dst) {
  int a = blockIdx.y;
  const float* sp = a == 0 ? s0 : a == 1 ? s1 : a == 2 ? s2 : s3;
  const float sc = (a == 0) ? QSCALE : 1.0f;
  size_t i = ((size_t)blockIdx.x * 256 + threadIdx.x) * 8;
  fx4 x = *(const fx4*)(sp + i);
  fx4 y = *(const fx4*)(sp + i + 4);
  bh8 o;
#pragma unroll
  for (int j = 0; j < 4; j++) { o[j] = f2bf(x[j] * sc); o[4 + j] = f2bf(y[j] * sc); }
  *(bh8*)(dst + (size_t)a * WSZ + i) = o;
}

__global__ __launch_bounds__(256) void cvt_act(const float* __restrict__ s0,
                                               const float* __restrict__ s1,
                                               const float* __restrict__ s2,
                                               short* __restrict__ dst) {
  int a = blockIdx.y;
  const float* sp = a == 0 ? s0 : a == 1 ? s1 : s2;
  size_t i = ((size_t)blockIdx.x * 256 + threadIdx.x) * 8;
  fx4 x = *(const fx4*)(sp + i);
  fx4 y = *(const fx4*)(sp + i + 4);
  bh8 o;
#pragma unroll
  for (int j = 0; j < 4; j++) { o[j] = f2bf(x[j]); o[4 + j] = f2bf(y[j]); }
  *(bh8*)(dst + (size_t)a * MSZ + i) = o;
}

// ---- m97-style NT GEMM, BK=32 (round-6 proven), XCD m-chunk ownership ----
// XCD = blockIdx.x (dispatch id % 8). Each XCD owns m-blocks [4x, 4x+4) for
// its z: A-slice 1MB + W 2MB -> L2-resident, cuts A HBM traffic ~8x.
template<bool OUTF32>
__global__ __launch_bounds__(256) void gemm_fast(const short* __restrict__ A0,
                                                 const short* __restrict__ A1,
                                                 const short* __restrict__ A2,
                                                 const short* __restrict__ W0,
                                                 void* __restrict__ C0)
{
  __shared__ short As[128 * 32];
  __shared__ short Bs[128 * 32];
  const int tid = threadIdx.x;
  const int lane = tid & 63, w = tid >> 6;
  const int lm = lane & 15, lg = lane >> 4;
  const int wr = w >> 1, wc = w & 1;
  const int mb = blockIdx.x * 4 + (blockIdx.y & 3);
  const int nb = blockIdx.y >> 2;
  const int m0 = mb * 128, n0 = nb * 128;
  const int z = blockIdx.z;
  const short* Ab = z == 0 ? A0 : z == 1 ? A1 : A2;
  const short* W = W0 + (size_t)z * WSZ;

  fx4 acc[4][4] = {};

  for (int k0 = 0; k0 < KK; k0 += 32) {
    __syncthreads();
#pragma unroll
    for (int c = 0; c < 2; c++) {
      int idx = c * 256 + tid;
      int row = idx >> 2, kc = idx & 3;
      gload16(W + (size_t)(n0 + row) * KK + k0 + kc * 8, Bs + idx * 8);
      gload16(Ab + (size_t)(m0 + row) * KK + k0 + kc * 8, As + idx * 8);
    }
    __syncthreads();
    bh8 af[4], bf[4];
#pragma unroll
    for (int mi = 0; mi < 4; mi++)
      af[mi] = *(const bh8*)&As[(wr * 64 + mi * 16 + lm) * 32 + lg * 8];
#pragma unroll
    for (int ni = 0; ni < 4; ni++)
      bf[ni] = *(const bh8*)&Bs[(wc * 64 + ni * 16 + lm) * 32 + lg * 8];
#pragma unroll
    for (int mi = 0; mi < 4; mi++)
#pragma unroll
      for (int ni = 0; ni < 4; ni++)
        acc[mi][ni] = __builtin_amdgcn_mfma_f32_16x16x32_bf16(af[mi], bf[ni], acc[mi][ni], 0, 0, 0);
  }

#pragma unroll
  for (int mi = 0; mi < 4; mi++)
#pragma unroll
    for (int ni = 0; ni < 4; ni++) {
      int row = m0 + wr * 64 + mi * 16 + lg * 4;
      int col = n0 + wc * 64 + ni * 16 + lm;
#pragma unroll
      for (int r = 0; r < 4; r++) {
        float vv = acc[mi][ni][r];
        if constexpr (OUTF32) ((float*)C0)[(size_t)z * MSZ + (size_t)(row + r) * NN + col] = vv;
        else ((short*)C0)[(size_t)z * MSZ + (size_t)(row + r) * NN + col] = f2bf(vv);
      }
    }
}

// ---- out-projection GEMM: 64x128 tiles, BK=32 (round-6 form), XCD m-chunk ----
__global__ __launch_bounds__(256) void gemm_out64(const short* __restrict__ A,
                                                  const short* __restrict__ W,
                                                  float* __restrict__ C)
{
  __shared__ short As[64 * 32];
  __shared__ short Bs[128 * 32];
  const int tid = threadIdx.x;
  const int lane = tid & 63, w = tid >> 6;
  const int lm = lane & 15, lg = lane >> 4;
  const int lin = blockIdx.x + 8 * blockIdx.y;
  const int swz = (lin & 7) * 64 + (lin >> 3);
  const int n0 = (swz & 7) * 128, m0 = (swz >> 3) * 64;

  fx4 acc[4][2] = {};

  for (int k0 = 0; k0 < KK; k0 += 32) {
    __syncthreads();
    {
      int row = tid >> 2, kc = tid & 3;
      gload16(A + (size_t)(m0 + row) * KK + k0 + kc * 8, As + tid * 8);
#pragma unroll
      for (int c = 0; c < 2; c++) {
        int idx = c * 256 + tid;
        int brow = idx >> 2, bkc = idx & 3;
        gload16(W + (size_t)(n0 + brow) * KK + k0 + bkc * 8, Bs + idx * 8);
      }
    }
    __syncthreads();
    bh8 af[4], bf[2];
#pragma unroll
    for (int mi = 0; mi < 4; mi++)
      af[mi] = *(const bh8*)&As[(mi * 16 + lm) * 32 + lg * 8];
#pragma unroll
    for (int ni = 0; ni < 2; ni++)
      bf[ni] = *(const bh8*)&Bs[(w * 32 + ni * 16 + lm) * 32 + lg * 8];
#pragma unroll
    for (int mi = 0; mi < 4; mi++)
#pragma unroll
      for (int ni = 0; ni < 2; ni++)
        acc[mi][ni] = __builtin_amdgcn_mfma_f32_16x16x32_bf16(af[mi], bf[ni], acc[mi][ni], 0, 0, 0);
  }

#pragma unroll
  for (int mi = 0; mi < 4; mi++)
#pragma unroll
    for (int ni = 0; ni < 2; ni++) {
      int row = m0 + mi * 16 + lg * 4;
      int col = n0 + w * 32 + ni * 16 + lm;
#pragma unroll
      for (int r = 0; r < 4; r++)
        C[(size_t)(row + r) * NN + col] = acc[mi][ni][r];
    }
}

// ---- fallback GEMM (f32 weights, reg-staged, padded LDS) ----
template<bool AF32, bool OUTF32>
__global__ __launch_bounds__(256) void gemm_nt(const void* __restrict__ Ap,
                                               const float* __restrict__ Bw,
                                               void* __restrict__ Cp,
                                               int M, int N, int K)
{
  __shared__ short As[128 * 40];
  __shared__ short Bs[128 * 40];
  const int tid = threadIdx.x;
  const int lane = tid & 63;
  const int w = tid >> 6;
  const int lm = lane & 15;
  const int lg = lane >> 4;
  const int wr = w >> 1, wc = w & 1;
  const int m0 = blockIdx.y * 128, n0 = blockIdx.x * 128;

  fx4 acc[4][4] = {};

  for (int k0 = 0; k0 < K; k0 += 32) {
    __syncthreads();
#pragma unroll
    for (int i = 0; i < 4; ++i) {
      int g = i * 256 + tid;
      int row = g >> 3, cg = g & 7;
      bh4 a4;
      if constexpr (AF32) {
        const float* A = (const float*)Ap;
        fx4 v = *(const fx4*)(A + (size_t)(m0 + row) * K + k0 + cg * 4);
#pragma unroll
        for (int j = 0; j < 4; j++) a4[j] = f2bf(v[j]);
      } else {
        const short* A = (const short*)Ap;
        a4 = *(const bh4*)(A + (size_t)(m0 + row) * K + k0 + cg * 4);
      }
      *(bh4*)&As[row * 40 + cg * 4] = a4;

      fx4 bv = *(const fx4*)(Bw + (size_t)(n0 + row) * K + k0 + cg * 4);
      bh4 b4;
#pragma unroll
      for (int j = 0; j < 4; j++) b4[j] = f2bf(bv[j]);
      *(bh4*)&Bs[row * 40 + cg * 4] = b4;
    }
    __syncthreads();

    bh8 af[4], bf[4];
#pragma unroll
    for (int mi = 0; mi < 4; mi++)
      af[mi] = *(const bh8*)&As[(wr * 64 + mi * 16 + lm) * 40 + lg * 8];
#pragma unroll
    for (int ni = 0; ni < 4; ni++)
      bf[ni] = *(const bh8*)&Bs[(wc * 64 + ni * 16 + lm) * 40 + lg * 8];
#pragma unroll
    for (int mi = 0; mi < 4; mi++)
#pragma unroll
      for (int ni = 0; ni < 4; ni++)
        acc[mi][ni] = __builtin_amdgcn_mfma_f32_16x16x32_bf16(af[mi], bf[ni], acc[mi][ni], 0, 0, 0);
  }

#pragma unroll
  for (int mi = 0; mi < 4; mi++) {
#pragma unroll
    for (int ni = 0; ni < 4; ni++) {
      int row = m0 + wr * 64 + mi * 16 + lg * 4;
      int col = n0 + wc * 64 + ni * 16 + lm;
#pragma unroll
      for (int r = 0; r < 4; r++) {
        float vv = acc[mi][ni][r];
        if constexpr (OUTF32) ((float*)Cp)[(size_t)(row + r) * N + col] = vv;
        else        ((short*)Cp)[(size_t)(row + r) * N + col] = f2bf(vv);
      }
    }
  }
}

// ---- causal flash attention: unpaired, single-buffer, DPP softmax, defer-max ----
// grid 1024 (1 q-tile per block, 4 blocks/CU). lin&7 = XCD owns heads
// [4x,4x+4) (K/V 2MB L2-resident); qt = 31-(lin>>5) -> per-XCD identical qt
// multiset (balanced) AND longest blocks dispatch first (LPT scheduling).
// LDS 25.6KB -> up to 6 blocks/CU resident. PRESCALED: Q carries QSCALE.
template<bool PRESCALED>
__global__ __launch_bounds__(256) void attn_kernel(const short* __restrict__ Q,
                                                   const short* __restrict__ Kb,
                                                   const short* __restrict__ Vb,
                                                   short* __restrict__ At)
{
  __shared__ short Kl[64 * 64]; // [kv][d] chunks, src-swizzled: LDS[row][ch] = K[row][ch^(row&7)]
  __shared__ short Vt[64 * 64]; // V^T [d][kv], chunk-swizzled by g(d)=((d>>3)+(d&7))&7
  __shared__ short Pl[4 * 16 * 72];

  const int tid = threadIdx.x;
  const int lane = tid & 63;
  const int w = tid >> 6;
  const int lm = lane & 15;
  const int lg = lane >> 4;
  const int lin = blockIdx.x;
  const int qt = 31 - (lin >> 5);
  const int bh = (lin & 7) * 4 + ((lin >> 3) & 3);
  const size_t headoff = (size_t)(bh >> 4) * T_DIM * E_DIM + (size_t)(bh & 15) * 64;
  const int q0 = qt * 64;

  const int r0 = tid >> 3, ch0 = tid & 7;
  const int r1 = (256 + tid) >> 3, ch1 = tid & 7;

  const int qrow = q0 + w * 16 + lm;
  bh8 qf[2];
#pragma unroll
  for (int ks = 0; ks < 2; ks++)
    qf[ks] = *(const bh8*)(Q + headoff + (size_t)qrow * E_DIM + ks * 32 + lg * 8);

  fx4 oacc[4] = {};
  float m_r[4], l_r[4];
#pragma unroll
  for (int r = 0; r < 4; r++) { m_r[r] = -INFINITY; l_r[r] = 0.0f; }

  for (int t = 0; t <= qt; ++t) {
    const int kv0 = t * 64;
    if (t) __syncthreads();   // previous tile's LDS reads done before overwrite
    // stage K (glds, src-swizzled) and V^T (reg scatter, chunk-swizzled)
    gload16(Kb + headoff + (size_t)(kv0 + r0) * E_DIM + ((ch0 ^ (r0 & 7)) * 8), &Kl[tid * 8]);
    gload16(Kb + headoff + (size_t)(kv0 + r1) * E_DIM + ((ch1 ^ (r1 & 7)) * 8), &Kl[(256 + tid) * 8]);
    {
      bh8 v8a = *(const bh8*)(Vb + headoff + (size_t)(kv0 + r0) * E_DIM + ch0 * 8);
      bh8 v8b = *(const bh8*)(Vb + headoff + (size_t)(kv0 + r1) * E_DIM + ch1 * 8);
#pragma unroll
      for (int j = 0; j < 8; j++) {
        int d = ch0 * 8 + j;
        Vt[d * 64 + (((r0 >> 3) ^ ((ch0 + j) & 7)) * 8) + (r0 & 7)] = v8a[j];
        Vt[d * 64 + (((r1 >> 3) ^ ((ch1 + j) & 7)) * 8) + (r1 & 7)] = v8b[j];
      }
    }
    __syncthreads();   // glds drained + V^T visible

    // S = Q K^T
    fx4 sacc[4] = {};
#pragma unroll
    for (int nb = 0; nb < 4; nb++) {
      const int rK = nb * 16 + lm;
#pragma unroll
      for (int ks = 0; ks < 2; ks++) {
        bh8 kf = *(const bh8*)&Kl[rK * 64 + (((ks * 4 + lg) ^ (lm & 7)) * 8)];
        sacc[nb] = __builtin_amdgcn_mfma_f32_16x16x32_bf16(qf[ks], kf, sacc[nb], 0, 0, 0);
      }
    }

    // (optional scale) + causal mask (diagonal tile only)
    float sv[4][4];
    const bool maskt = (t == qt);
#pragma unroll
    for (int nb = 0; nb < 4; nb++)
#pragma unroll
      for (int r = 0; r < 4; r++) {
        float x = PRESCALED ? sacc[nb][r] : sacc[nb][r] * QSCALE;
        if (maskt && (nb * 16 + lm > w * 16 + lg * 4 + r)) x = -INFINITY;
        sv[nb][r] = x;
      }

    // row maxes (DPP) + defer-max: skip rescale when no row max grew
    float rm4[4];
    bool stable = true;
#pragma unroll
    for (int r = 0; r < 4; r++) {
      float rm = fmaxf(fmaxf(sv[0][r], sv[1][r]), fmaxf(sv[2][r], sv[3][r]));
      rm = rowmax16(rm);
      rm4[r] = rm;
      stable = stable && (rm <= m_r[r]);
    }
    if (!__all(stable)) {
#pragma unroll
      for (int r = 0; r < 4; r++) {
        float mn = fmaxf(m_r[r], rm4[r]);
        float fac = exp2f(m_r[r] - mn);
        l_r[r] *= fac;
        m_r[r] = mn;
#pragma unroll
        for (int db = 0; db < 4; db++) oacc[db][r] *= fac;
      }
    }
    float p[4][4];
#pragma unroll
    for (int r = 0; r < 4; r++) {
      float ps = 0.0f;
#pragma unroll
      for (int nb = 0; nb < 4; nb++) { p[nb][r] = exp2f(sv[nb][r] - m_r[r]); ps += p[nb][r]; }
      ps = rowsum16(ps);
      l_r[r] += ps;
    }

    // P -> per-wave LDS (no barrier: per-wave private, same-wave DS in-order)
#pragma unroll
    for (int nb = 0; nb < 4; nb++)
#pragma unroll
      for (int r = 0; r < 4; r++)
        Pl[w * 1152 + (lg * 4 + r) * 72 + nb * 16 + lm] = f2bf(p[nb][r]);

    // O += P V
    bh8 pa[2];
#pragma unroll
    for (int ks = 0; ks < 2; ks++)
      pa[ks] = *(const bh8*)&Pl[w * 1152 + lm * 72 + ks * 32 + lg * 8];
#pragma unroll
    for (int db = 0; db < 4; db++) {
      const int d = db * 16 + lm;
      const int gsw = ((d >> 3) + (d & 7)) & 7;
#pragma unroll
      for (int ks = 0; ks < 2; ks++) {
        bh8 vf = *(const bh8*)&Vt[d * 64 + (((ks * 4 + lg) ^ gsw) * 8)];
        oacc[db] = __builtin_amdgcn_mfma_f32_16x16x32_bf16(pa[ks], vf, oacc[db], 0, 0, 0);
      }
    }
  }

  // epilogue
#pragma unroll
  for (int r = 0; r < 4; r++) {
    float rl = 1.0f / l_r[r];
    int row = q0 + w * 16 + lg * 4 + r;
#pragma unroll
    for (int db = 0; db < 4; db++)
      At[headoff + (size_t)row * E_DIM + db * 16 + lm] = f2bf(oacc[db][r] * rl);
  }
}

extern "C" void kernel_launch(void* const* d_in, const int* in_sizes, int n_in,
                              void* d_out, int out_size, void* d_ws, size_t ws_size,
                              hipStream_t stream)
{
  const float* q  = (const float*)d_in[0];
  const float* k  = (const float*)d_in[1];
  const float* v  = (const float*)d_in[2];
  // d_in[3] = causal mask, statically known -> ignored
  const float* Wq = (const float*)d_in[4];
  const float* Wk = (const float*)d_in[5];
  const float* Wv = (const float*)d_in[6];
  const float* Wo = (const float*)d_in[7];

  short* Qb  = (short*)d_ws;            // 3 x [4096,1024] bf16 projections
  short* Kbb = Qb + MSZ;
  short* Vbb = Kbb + MSZ;
  short* wqb = Vbb + MSZ;               // 4 x [1024,1024] bf16 weights (Wq pre-scaled)
  short* Xq  = wqb + 4 * WSZ;           // 3 x [4096,1024] bf16 activations
  short* At  = Xq;                      // alias: At live only after Xq dead

  const size_t need_full = (3 * MSZ + 4 * WSZ + 3 * MSZ) * 2;      // ~56 MB

  if (ws_size >= need_full) {
    cvt_act<<<dim3(MSZ / (256 * 8), 3), 256, 0, stream>>>(q, k, v, Xq);
    cvt_w<<<dim3(WSZ / (256 * 8), 4), 256, 0, stream>>>(Wq, Wk, Wv, Wo, wqb);
    gemm_fast<false><<<dim3(8, 32, 3), 256, 0, stream>>>(
        Xq, Xq + MSZ, Xq + 2 * MSZ, wqb, Qb);
    attn_kernel<true><<<1024, 256, 0, stream>>>(Qb, Kbb, Vbb, At);
    gemm_out64<<<dim3(NN / 128, MM / 64), 256, 0, stream>>>(
        At, wqb + 3 * WSZ, (float*)d_out);
  } else {
    short* At2 = Vbb + MSZ;
    dim3 gg(NN / 128, MM / 128);
    gemm_nt<true, false><<<gg, 256, 0, stream>>>(q, Wq, Qb, MM, NN, KK);
    gemm_nt<true, false><<<gg, 256, 0, stream>>>(k, Wk, Kbb, MM, NN, KK);
    gemm_nt<true, false><<<gg, 256, 0, stream>>>(v, Wv, Vbb, MM, NN, KK);
    attn_kernel<false><<<1024, 256, 0, stream>>>(Qb, Kbb, Vbb, At2);
    gemm_nt<false, true><<<gg, 256, 0, stream>>>(At2, Wo, d_out, MM, NN, KK);
  }
}